// Round 1
// baseline (8737.419 us; speedup 1.0000x reference)
//
#include <hip/hip_runtime.h>
#include <math.h>

// MinimalRNN: S=256 steps, B=256 batch, H=1024, L=3 layers.
// y[t] = h_2(t), h_N = h_l(255).  out = [y (S*B*H) | h_N (L*B*H)] fp32.
//
// Round-2 design changes vs round-1 (12830 us):
//  * spin_wait polls RELAXED (round-1 polled ACQUIRE -> buffer_inv L2
//    invalidate per poll iteration = XCD-wide invalidation storm).  A single
//    explicit agent acquire fence after the barrier provides the ordering.
//  * Waits reordered: layer 0 runs its x-GEMM before any wait; layers 1-2 run
//    the recurrent GEMM (own t-1 data) first and wait for layer l-1's step-t
//    flag only afterwards, hiding inter-layer sync latency under MFMA.
//  * Flags split per (layer, t, row-block): fan-in 32 instead of 64; each
//    consumer only depends on the 32 producers of its own 128-row block.
//  * x optionally pre-converted to fp16 in the pre-kernel (guarded by
//    ws_size; fp32 fallback path kept) -> layer-0 inner loop matches the
//    other layers (no cvt, half the A-bytes).
//
// Topology: 192 persistent WGs (3 layers x 2 row-blocks x 32 col-blocks),
// 256 threads, 1 WG/CU (128 KiB LDS).  Each WG owns a [128 x 32] output
// slice; weight slice [32 x 2048] lives in LDS as fp16 in MFMA B-fragment
// order.  Activations ring-buffered (depth 4) in ws as fp16; producer/
// consumer sync via per-(layer,t,rb) counters with agent-scope atomics.

#define S_LEN  256
#define BATCH  256
#define HID    1024
#define NLAY   3
#define RING   4
#define COLS   32
#define ROWS   128
#define GROUP  32          // producers per (layer, row-block) flag
#define TOTAL_WG     192
#define THREADS      256

typedef _Float16 v8h __attribute__((ext_vector_type(8)));
typedef float    v4f __attribute__((ext_vector_type(4)));

#define MFMA16(a, b, c) __builtin_amdgcn_mfma_f32_16x16x32_f16((a), (b), (c), 0, 0, 0)

// flag index: (l, t, rb) -> ((l*S + t)*2 + rb); 1536 ints total.
#define FLAG(l, t, rb) (((l) * S_LEN + (t)) * 2 + (rb))

__device__ __forceinline__ void spin_wait(int* p, int target) {
  // RELAXED poll: no per-iteration cache invalidate.  The caller issues one
  // agent-scope acquire fence after the workgroup barrier.
  while (__hip_atomic_load(p, __ATOMIC_RELAXED, __HIP_MEMORY_SCOPE_AGENT) < target) {
    __builtin_amdgcn_s_sleep(1);
  }
}

// Pre-kernel: zero flags, seed ring slot (RING-1) with h_0, optionally
// convert x to fp16.  ws is re-poisoned before every launch -> must rerun.
__global__ void rnn_pre(const float* __restrict__ x,
                        const float* __restrict__ h0,
                        _Float16* __restrict__ hring,
                        _Float16* __restrict__ x16,
                        int* __restrict__ done,
                        int convert_x) {
  const size_t idx = (size_t)blockIdx.x * blockDim.x + threadIdx.x;
  if (idx < NLAY * S_LEN * 2) done[idx] = 0;
  if (idx < (size_t)NLAY * BATCH * HID) {
    const int l   = (int)(idx / (BATCH * HID));
    const int off = (int)(idx - (size_t)l * (BATCH * HID));
    hring[(size_t)(l * RING + (RING - 1)) * BATCH * HID + off] = (_Float16)h0[idx];
  }
  if (convert_x) {
    const size_t base = idx * 8;
    if (base < (size_t)S_LEN * BATCH * HID) {
      v4f f0 = *(const v4f*)(x + base);
      v4f f1 = *(const v4f*)(x + base + 4);
      v8h v;
#pragma unroll
      for (int j = 0; j < 4; ++j) {
        v[j]     = (_Float16)f0[j];
        v[j + 4] = (_Float16)f1[j];
      }
      *(v8h*)(x16 + base) = v;
    }
  }
}

__global__ __launch_bounds__(THREADS, 1) void rnn_main(
    const float* __restrict__ x,
    const _Float16* __restrict__ x16,   // nullptr -> use fp32 x path
    const float* __restrict__ W_ih, const float* __restrict__ W_hh,
    const float* __restrict__ b_ih, const float* __restrict__ b_hh,
    float* __restrict__ out,
    _Float16* __restrict__ hring, int* __restrict__ done) {
  // B-fragment-swizzled weight slice: [kc 0..63][col-tile 0..1][lane][8 fp16]
  // kc*32 spans concatenated K: k<1024 -> W_ih, k>=1024 -> W_hh.
  __shared__ _Float16 WB[64][2][64][8];  // 128 KiB

  const int tid  = threadIdx.x;
  const int lane = tid & 63;
  const int wave = tid >> 6;
  const int wg   = blockIdx.x;
  const int l    = wg >> 6;   // 64 WGs per layer
  const int sub  = wg & 63;
  const int rb   = sub >> 5;  // row-block 0..1
  const int cb   = sub & 31;  // col-block 0..31

  // ---- one-time: stage weight slice into LDS (fp32 -> fp16, swizzled) ----
  for (int i = tid; i < 64 * 2 * 64; i += THREADS) {
    const int kc = i >> 7;
    const int ct = (i >> 6) & 1;
    const int ln = i & 63;
    const int c    = ct * 16 + (ln & 15);
    const int k0   = kc * 32 + ((ln >> 4) << 3);
    const int gcol = cb * COLS + c;
    const float* src = (k0 < HID)
        ? (W_ih + (size_t)l * HID * HID + (size_t)gcol * HID + k0)
        : (W_hh + (size_t)l * HID * HID + (size_t)gcol * HID + (k0 - HID));
    v8h w;
#pragma unroll
    for (int j = 0; j < 8; ++j) w[j] = (_Float16)src[j];
    *(v8h*)(&WB[kc][ct][ln][0]) = w;
  }

  const int   c0    = cb * COLS + (lane & 15);
  const float bias0 = b_ih[l * HID + c0]      + b_hh[l * HID + c0];
  const float bias1 = b_ih[l * HID + c0 + 16] + b_hh[l * HID + c0 + 16];
  __syncthreads();

  const int rowbase = rb * ROWS + wave * 32;  // this wave's 32 rows
  const int r0      = rowbase + (lane & 15);
  const int kfrag   = (lane >> 4) << 3;       // quad*8

  for (int t = 0; t < S_LEN; ++t) {
    v4f acc[2][2];
#pragma unroll
    for (int a = 0; a < 2; ++a)
#pragma unroll
      for (int b = 0; b < 2; ++b) acc[a][b] = (v4f){0.f, 0.f, 0.f, 0.f};

    // ---- layer 0: x-GEMM needs no synchronization -> run before any wait
    if (l == 0) {
      if (x16) {
        const _Float16* a0p = x16 + (size_t)t * BATCH * HID + (size_t)r0 * HID + kfrag;
        const _Float16* a1p = a0p + (size_t)16 * HID;
#pragma unroll 8
        for (int kc = 0; kc < 32; ++kc) {
          v8h a0 = *(const v8h*)(a0p + kc * 32);
          v8h a1 = *(const v8h*)(a1p + kc * 32);
          v8h b0 = *(const v8h*)(&WB[kc][0][lane][0]);
          v8h b1 = *(const v8h*)(&WB[kc][1][lane][0]);
          acc[0][0] = MFMA16(a0, b0, acc[0][0]);
          acc[0][1] = MFMA16(a0, b1, acc[0][1]);
          acc[1][0] = MFMA16(a1, b0, acc[1][0]);
          acc[1][1] = MFMA16(a1, b1, acc[1][1]);
        }
      } else {
        const float* a0p = x + (size_t)t * BATCH * HID + (size_t)r0 * HID + kfrag;
        const float* a1p = a0p + (size_t)16 * HID;
#pragma unroll 4
        for (int kc = 0; kc < 32; ++kc) {
          v4f f0 = *(const v4f*)(a0p + kc * 32);
          v4f f1 = *(const v4f*)(a0p + kc * 32 + 4);
          v4f g0 = *(const v4f*)(a1p + kc * 32);
          v4f g1 = *(const v4f*)(a1p + kc * 32 + 4);
          v8h a0, a1;
#pragma unroll
          for (int j = 0; j < 4; ++j) {
            a0[j]     = (_Float16)f0[j];
            a0[j + 4] = (_Float16)f1[j];
            a1[j]     = (_Float16)g0[j];
            a1[j + 4] = (_Float16)g1[j];
          }
          v8h b0 = *(const v8h*)(&WB[kc][0][lane][0]);
          v8h b1 = *(const v8h*)(&WB[kc][1][lane][0]);
          acc[0][0] = MFMA16(a0, b0, acc[0][0]);
          acc[0][1] = MFMA16(a0, b1, acc[0][1]);
          acc[1][0] = MFMA16(a1, b0, acc[1][0]);
          acc[1][1] = MFMA16(a1, b1, acc[1][1]);
        }
      }
    }

    // ---- sync 1: own layer t-1 (recurrent data) + ring-free slot ----
    if (tid == 0) {
      if (t > 0)                      spin_wait(&done[FLAG(l, t - 1, rb)], GROUP);
      if (l < NLAY - 1 && t >= RING)  spin_wait(&done[FLAG(l + 1, t - RING, rb)], GROUP);
    }
    __syncthreads();
    __builtin_amdgcn_fence(__ATOMIC_ACQUIRE, "agent");

    // ---- GEMM part 2: h_prev @ W_hh^T  (K = 1024..2047) ----
    {
      const _Float16* base = hring + (size_t)(l * RING + ((t + RING - 1) & (RING - 1))) * BATCH * HID;
      const _Float16* a0p  = base + (size_t)r0 * HID + kfrag;
      const _Float16* a1p  = a0p + (size_t)16 * HID;
#pragma unroll 8
      for (int kc = 0; kc < 32; ++kc) {
        v8h a0 = *(const v8h*)(a0p + kc * 32);
        v8h a1 = *(const v8h*)(a1p + kc * 32);
        v8h b0 = *(const v8h*)(&WB[kc + 32][0][lane][0]);
        v8h b1 = *(const v8h*)(&WB[kc + 32][1][lane][0]);
        acc[0][0] = MFMA16(a0, b0, acc[0][0]);
        acc[0][1] = MFMA16(a0, b1, acc[0][1]);
        acc[1][0] = MFMA16(a1, b0, acc[1][0]);
        acc[1][1] = MFMA16(a1, b1, acc[1][1]);
      }
    }

    // ---- sync 2 + GEMM part 1 for layers 1..2: inp @ W_ih^T ----
    if (l > 0) {
      if (tid == 0) spin_wait(&done[FLAG(l - 1, t, rb)], GROUP);
      __syncthreads();
      __builtin_amdgcn_fence(__ATOMIC_ACQUIRE, "agent");

      const _Float16* base = hring + (size_t)((l - 1) * RING + (t & (RING - 1))) * BATCH * HID;
      const _Float16* a0p  = base + (size_t)r0 * HID + kfrag;
      const _Float16* a1p  = a0p + (size_t)16 * HID;
#pragma unroll 8
      for (int kc = 0; kc < 32; ++kc) {
        v8h a0 = *(const v8h*)(a0p + kc * 32);
        v8h a1 = *(const v8h*)(a1p + kc * 32);
        v8h b0 = *(const v8h*)(&WB[kc][0][lane][0]);
        v8h b1 = *(const v8h*)(&WB[kc][1][lane][0]);
        acc[0][0] = MFMA16(a0, b0, acc[0][0]);
        acc[0][1] = MFMA16(a0, b1, acc[0][1]);
        acc[1][0] = MFMA16(a1, b0, acc[1][0]);
        acc[1][1] = MFMA16(a1, b1, acc[1][1]);
      }
    }

    // ---- epilogue: bias + tanh, write ring (fp16), y / h_N (fp32) ----
    // C/D layout: col = lane&15 (+16*ct), row = (lane>>4)*4 + reg (+16*rt).
    _Float16* hout = hring + (size_t)(l * RING + (t & (RING - 1))) * BATCH * HID;
    float*    yout = out + (size_t)t * BATCH * HID;
    float*    hN   = out + (size_t)S_LEN * BATCH * HID + (size_t)l * BATCH * HID;
    const int qrow = (lane >> 4) << 2;
    const int ccol = lane & 15;
#pragma unroll
    for (int rt = 0; rt < 2; ++rt) {
#pragma unroll
      for (int ct = 0; ct < 2; ++ct) {
        const float bb   = (ct == 0) ? bias0 : bias1;
        const int   colg = cb * COLS + ct * 16 + ccol;
#pragma unroll
        for (int i = 0; i < 4; ++i) {
          const int rowg = rowbase + rt * 16 + qrow + i;
          const float hv = tanhf(acc[rt][ct][i] + bb);
          hout[(size_t)rowg * HID + colg] = (_Float16)hv;
          if (l == NLAY - 1)  yout[(size_t)rowg * HID + colg] = hv;
          if (t == S_LEN - 1) hN[(size_t)rowg * HID + colg]   = hv;
        }
      }
    }

    // ---- publish: drain all waves' stores, then release-increment flag ----
    __syncthreads();
    if (tid == 0) {
      __hip_atomic_fetch_add(&done[FLAG(l, t, rb)], 1, __ATOMIC_RELEASE, __HIP_MEMORY_SCOPE_AGENT);
    }
  }
}

extern "C" void kernel_launch(void* const* d_in, const int* in_sizes, int n_in,
                              void* d_out, int out_size, void* d_ws, size_t ws_size,
                              hipStream_t stream) {
  (void)in_sizes; (void)n_in; (void)out_size;
  const float* x    = (const float*)d_in[0];
  const float* h0   = (const float*)d_in[1];
  const float* W_ih = (const float*)d_in[2];
  const float* W_hh = (const float*)d_in[3];
  const float* b_ih = (const float*)d_in[4];
  const float* b_hh = (const float*)d_in[5];
  float* out = (float*)d_out;

  int*      done  = (int*)d_ws;                        // 1536 counters (6 KiB)
  _Float16* hring = (_Float16*)((char*)d_ws + 8192);   // L*RING*B*H fp16 = 6 MiB

  const size_t ring_bytes = (size_t)NLAY * RING * BATCH * HID * sizeof(_Float16);
  const size_t x16_off    = 8192 + ring_bytes;
  const size_t x16_bytes  = (size_t)S_LEN * BATCH * HID * sizeof(_Float16);  // 128 MiB
  const int    use_x16    = (ws_size >= x16_off + x16_bytes) ? 1 : 0;
  _Float16*    x16        = use_x16 ? (_Float16*)((char*)d_ws + x16_off) : (_Float16*)0;

  const int pre_elems  = use_x16 ? (S_LEN * BATCH * HID / 8) : (NLAY * BATCH * HID);
  const int pre_blocks = (pre_elems + THREADS - 1) / THREADS;
  rnn_pre<<<pre_blocks, THREADS, 0, stream>>>(x, h0, hring, x16, done, use_x16);
  rnn_main<<<TOTAL_WG, THREADS, 0, stream>>>(x, x16, W_ih, W_hh, b_ih, b_hh, out, hring, done);
}

// Round 2
// 8445.456 us; speedup vs baseline: 1.0346x; 1.0346x over previous
//
#include <hip/hip_runtime.h>
#include <math.h>

// MinimalRNN: S=256 steps, B=256 batch, H=1024, L=3 layers.
// y[t] = h_2(t), h_N = h_l(255).  out = [y (S*B*H) | h_N (L*B*H)] fp32.
//
// Round-3 changes vs round-2 (8737 us, MfmaUtil 3.9%, VALUBusy 3.6%,
// 32.7 us/step => latency-bound):
//  * 512 threads/WG (8 waves, 16 rows each) -> 2 waves/SIMD.  Round-2 ran
//    1 wave/SIMD; every post-fence LLC miss (~600-900 cyc) was exposed.
//  * GEMM1 (input @ W_ih) moved OFF the recurrent critical path: layer l-1
//    leads layer l in steady state, so its flag is already set -> wait is
//    non-blocking.  Critical chain is now notice + fence + GEMM2 only.
//  * One __syncthreads per step (pre-publish drain).  Waves spin on flags
//    themselves (relaxed, coalesced) and fence per-wave -> staggered starts,
//    no barrier-release latency on the wait side.
//  * RING 4 -> 8 (12 MiB) for inter-layer jitter slack.
//  * tanh via native exp2: error ~1e-7 << fp16 quantization (absmax 0.0039).
//
// Topology: 192 persistent WGs (3 layers x 2 row-blocks x 32 col-blocks),
// 512 threads, 1 WG/CU (128 KiB LDS).  Each WG owns a [128 x 32] output
// slice; weight slice [32 x 2048] in LDS as fp16 MFMA B-fragments.
// Activations ring-buffered in ws as fp16; sync via per-(layer,t,rowblock)
// counters, relaxed polls + explicit agent acquire fences.

#define S_LEN  256
#define BATCH  256
#define HID    1024
#define NLAY   3
#define RING   8
#define COLS   32
#define ROWS   128
#define GROUP  32          // producers per (layer, row-block) flag
#define TOTAL_WG     192
#define THREADS      512

typedef _Float16 v8h __attribute__((ext_vector_type(8)));
typedef float    v4f __attribute__((ext_vector_type(4)));

#define MFMA16(a, b, c) __builtin_amdgcn_mfma_f32_16x16x32_f16((a), (b), (c), 0, 0, 0)

// flag index: (l, t, rb) -> ((l*S + t)*2 + rb); 1536 ints total.
#define FLAG(l, t, rb) (((l) * S_LEN + (t)) * 2 + (rb))

__device__ __forceinline__ void wave_wait(int* p, int target) {
  // All lanes poll the same dword (coalesces to one request per wave).
  // RELAXED: no per-poll cache invalidate; caller fences after.
  while (__hip_atomic_load(p, __ATOMIC_RELAXED, __HIP_MEMORY_SCOPE_AGENT) < target) {
    __builtin_amdgcn_s_sleep(1);
  }
}

__device__ __forceinline__ float tanh_fast(float x) {
  // tanh(x) = 1 - 2/(e^{2x}+1); exact at +-inf overflow, error ~1e-7.
  const float e = __expf(2.0f * x);
  return 1.0f - 2.0f * __builtin_amdgcn_rcpf(e + 1.0f);
}

// Pre-kernel: zero flags, seed ring slot (RING-1) with h_0, optionally
// convert x to fp16.  ws is re-poisoned before every launch -> must rerun.
__global__ void rnn_pre(const float* __restrict__ x,
                        const float* __restrict__ h0,
                        _Float16* __restrict__ hring,
                        _Float16* __restrict__ x16,
                        int* __restrict__ done,
                        int convert_x) {
  const size_t idx = (size_t)blockIdx.x * blockDim.x + threadIdx.x;
  if (idx < NLAY * S_LEN * 2) done[idx] = 0;
  if (idx < (size_t)NLAY * BATCH * HID) {
    const int l   = (int)(idx / (BATCH * HID));
    const int off = (int)(idx - (size_t)l * (BATCH * HID));
    hring[(size_t)(l * RING + (RING - 1)) * BATCH * HID + off] = (_Float16)h0[idx];
  }
  if (convert_x) {
    const size_t base = idx * 8;
    if (base < (size_t)S_LEN * BATCH * HID) {
      v4f f0 = *(const v4f*)(x + base);
      v4f f1 = *(const v4f*)(x + base + 4);
      v8h v;
#pragma unroll
      for (int j = 0; j < 4; ++j) {
        v[j]     = (_Float16)f0[j];
        v[j + 4] = (_Float16)f1[j];
      }
      *(v8h*)(x16 + base) = v;
    }
  }
}

__global__ __launch_bounds__(THREADS, 1) void rnn_main(
    const float* __restrict__ x,
    const _Float16* __restrict__ x16,   // nullptr -> fp32 x path
    const float* __restrict__ W_ih, const float* __restrict__ W_hh,
    const float* __restrict__ b_ih, const float* __restrict__ b_hh,
    float* __restrict__ out,
    _Float16* __restrict__ hring, int* __restrict__ done) {
  // B-fragment-swizzled weight slice: [kc 0..63][col-tile 0..1][lane][8 fp16]
  // kc*32 spans concatenated K: k<1024 -> W_ih, k>=1024 -> W_hh.
  __shared__ _Float16 WB[64][2][64][8];  // 128 KiB

  const int tid  = threadIdx.x;
  const int lane = tid & 63;
  const int wave = tid >> 6;   // 0..7
  const int wg   = blockIdx.x;
  const int l    = wg >> 6;    // 64 WGs per layer
  const int sub  = wg & 63;
  const int rb   = sub >> 5;   // row-block 0..1
  const int cb   = sub & 31;   // col-block 0..31

  // ---- one-time: stage weight slice into LDS (fp32 -> fp16, swizzled) ----
  for (int i = tid; i < 64 * 2 * 64; i += THREADS) {
    const int kc = i >> 7;
    const int ct = (i >> 6) & 1;
    const int ln = i & 63;
    const int c    = ct * 16 + (ln & 15);
    const int k0   = kc * 32 + ((ln >> 4) << 3);
    const int gcol = cb * COLS + c;
    const float* src = (k0 < HID)
        ? (W_ih + (size_t)l * HID * HID + (size_t)gcol * HID + k0)
        : (W_hh + (size_t)l * HID * HID + (size_t)gcol * HID + (k0 - HID));
    v8h w;
#pragma unroll
    for (int j = 0; j < 8; ++j) w[j] = (_Float16)src[j];
    *(v8h*)(&WB[kc][ct][ln][0]) = w;
  }

  const int   c0    = cb * COLS + (lane & 15);
  const float bias0 = b_ih[l * HID + c0]      + b_hh[l * HID + c0];
  const float bias1 = b_ih[l * HID + c0 + 16] + b_hh[l * HID + c0 + 16];
  __syncthreads();

  const int rowbase = rb * ROWS + wave * 16;  // this wave's 16 rows
  const int r0      = rowbase + (lane & 15);
  const int kfrag   = (lane >> 4) << 3;       // quad*8

  for (int t = 0; t < S_LEN; ++t) {
    v4f acc[2];
    acc[0] = (v4f){0.f, 0.f, 0.f, 0.f};
    acc[1] = (v4f){0.f, 0.f, 0.f, 0.f};

    // ---- GEMM 1: inp @ W_ih^T (K = 0..1023).  For l>0 the producer layer
    // leads in steady state, so this wait is (nearly) non-blocking.
    if (l == 0) {
      if (x16) {
        const _Float16* ap = x16 + (size_t)t * BATCH * HID + (size_t)r0 * HID + kfrag;
#pragma unroll 8
        for (int kc = 0; kc < 32; ++kc) {
          v8h a  = *(const v8h*)(ap + kc * 32);
          v8h b0 = *(const v8h*)(&WB[kc][0][lane][0]);
          v8h b1 = *(const v8h*)(&WB[kc][1][lane][0]);
          acc[0] = MFMA16(a, b0, acc[0]);
          acc[1] = MFMA16(a, b1, acc[1]);
        }
      } else {
        const float* ap = x + (size_t)t * BATCH * HID + (size_t)r0 * HID + kfrag;
#pragma unroll 4
        for (int kc = 0; kc < 32; ++kc) {
          v4f f0 = *(const v4f*)(ap + kc * 32);
          v4f f1 = *(const v4f*)(ap + kc * 32 + 4);
          v8h a;
#pragma unroll
          for (int j = 0; j < 4; ++j) {
            a[j]     = (_Float16)f0[j];
            a[j + 4] = (_Float16)f1[j];
          }
          v8h b0 = *(const v8h*)(&WB[kc][0][lane][0]);
          v8h b1 = *(const v8h*)(&WB[kc][1][lane][0]);
          acc[0] = MFMA16(a, b0, acc[0]);
          acc[1] = MFMA16(a, b1, acc[1]);
        }
      }
    } else {
      wave_wait(&done[FLAG(l - 1, t, rb)], GROUP);
      __builtin_amdgcn_fence(__ATOMIC_ACQUIRE, "agent");
      const _Float16* ap = hring
          + (size_t)((l - 1) * RING + (t & (RING - 1))) * BATCH * HID
          + (size_t)r0 * HID + kfrag;
#pragma unroll 8
      for (int kc = 0; kc < 32; ++kc) {
        v8h a  = *(const v8h*)(ap + kc * 32);
        v8h b0 = *(const v8h*)(&WB[kc][0][lane][0]);
        v8h b1 = *(const v8h*)(&WB[kc][1][lane][0]);
        acc[0] = MFMA16(a, b0, acc[0]);
        acc[1] = MFMA16(a, b1, acc[1]);
      }
    }

    // ---- recurrent wait (the critical chain) + ring-free check ----
    if (t > 0)                      wave_wait(&done[FLAG(l, t - 1, rb)], GROUP);
    if (l < NLAY - 1 && t >= RING)  wave_wait(&done[FLAG(l + 1, t - RING, rb)], GROUP);
    __builtin_amdgcn_fence(__ATOMIC_ACQUIRE, "agent");

    // ---- GEMM 2: h_prev @ W_hh^T (K = 1024..2047) ----
    {
      const _Float16* ap = hring
          + (size_t)(l * RING + ((t + RING - 1) & (RING - 1))) * BATCH * HID
          + (size_t)r0 * HID + kfrag;
#pragma unroll 8
      for (int kc = 0; kc < 32; ++kc) {
        v8h a  = *(const v8h*)(ap + kc * 32);
        v8h b0 = *(const v8h*)(&WB[kc + 32][0][lane][0]);
        v8h b1 = *(const v8h*)(&WB[kc + 32][1][lane][0]);
        acc[0] = MFMA16(a, b0, acc[0]);
        acc[1] = MFMA16(a, b1, acc[1]);
      }
    }

    // ---- epilogue: bias + tanh, write ring (fp16), y / h_N (fp32) ----
    // C/D layout: col = lane&15 (+16*ct), row = (lane>>4)*4 + i.
    _Float16* hout = hring + (size_t)(l * RING + (t & (RING - 1))) * BATCH * HID;
    float*    yout = out + (size_t)t * BATCH * HID;
    float*    hN   = out + (size_t)S_LEN * BATCH * HID + (size_t)l * BATCH * HID;
    const int qrow = (lane >> 4) << 2;
    const int ccol = lane & 15;
#pragma unroll
    for (int ct = 0; ct < 2; ++ct) {
      const float bb   = (ct == 0) ? bias0 : bias1;
      const int   colg = cb * COLS + ct * 16 + ccol;
#pragma unroll
      for (int i = 0; i < 4; ++i) {
        const int rowg = rowbase + qrow + i;
        const float hv = tanh_fast(acc[ct][i] + bb);
        hout[(size_t)rowg * HID + colg] = (_Float16)hv;
        if (l == NLAY - 1)  yout[(size_t)rowg * HID + colg] = hv;
        if (t == S_LEN - 1) hN[(size_t)rowg * HID + colg]   = hv;
      }
    }

    // ---- publish: drain all waves' stores, then release-increment flag ----
    __syncthreads();
    if (tid == 0) {
      __hip_atomic_fetch_add(&done[FLAG(l, t, rb)], 1, __ATOMIC_RELEASE, __HIP_MEMORY_SCOPE_AGENT);
    }
  }
}

extern "C" void kernel_launch(void* const* d_in, const int* in_sizes, int n_in,
                              void* d_out, int out_size, void* d_ws, size_t ws_size,
                              hipStream_t stream) {
  (void)in_sizes; (void)n_in; (void)out_size;
  const float* x    = (const float*)d_in[0];
  const float* h0   = (const float*)d_in[1];
  const float* W_ih = (const float*)d_in[2];
  const float* W_hh = (const float*)d_in[3];
  const float* b_ih = (const float*)d_in[4];
  const float* b_hh = (const float*)d_in[5];
  float* out = (float*)d_out;

  int*      done  = (int*)d_ws;                        // 1536 counters (6 KiB)
  _Float16* hring = (_Float16*)((char*)d_ws + 8192);   // L*RING*B*H fp16 = 12 MiB

  const size_t ring_bytes = (size_t)NLAY * RING * BATCH * HID * sizeof(_Float16);
  const size_t x16_off    = 8192 + ring_bytes;
  const size_t x16_bytes  = (size_t)S_LEN * BATCH * HID * sizeof(_Float16);  // 128 MiB
  const int    use_x16    = (ws_size >= x16_off + x16_bytes) ? 1 : 0;
  _Float16*    x16        = use_x16 ? (_Float16*)((char*)d_ws + x16_off) : (_Float16*)0;

  const int pre_threads = 256;
  const size_t pre_elems = use_x16 ? ((size_t)S_LEN * BATCH * HID / 8)
                                   : ((size_t)NLAY * BATCH * HID);
  const int pre_blocks = (int)((pre_elems + pre_threads - 1) / pre_threads);
  rnn_pre<<<pre_blocks, pre_threads, 0, stream>>>(x, h0, hring, x16, done, use_x16);
  rnn_main<<<TOTAL_WG, THREADS, 0, stream>>>(x, x16, W_ih, W_hh, b_ih, b_hh, out, hring, done);
}